// Round 2
// baseline (170.413 us; speedup 1.0000x reference)
//
#include <hip/hip_runtime.h>
#include <math.h>

// Problem constants (fixed by setup_inputs)
constexpr int N_ = 8, C_ = 256, F_ = 16, WH_ = 784;
constexpr int NF = N_ * F_;          // 128
constexpr int CH_STRIDE = F_ * WH_;  // 12544 floats between channels
constexpr int SPLITS = 16;           // channel splits in K1
constexpr int CPS = C_ / SPLITS;     // 16 channels per split
constexpr int COUT_SZ = NF * WH_;    // 100352 floats (c output)
constexpr int P4 = WH_ / 4;          // 196 float4 per spatial row

__device__ inline float wave_reduce_sum(float v) {
#pragma unroll
  for (int o = 32; o > 0; o >>= 1) v += __shfl_down(v, o, 64);
  return v;
}
__device__ inline float wave_reduce_max(float v) {
#pragma unroll
  for (int o = 32; o > 0; o >>= 1) v = fmaxf(v, __shfl_down(v, o, 64));
  return v;
}

// ---- K1: partial channel-dot. Block b: nf = b>>4, split s = b&15.
// part[(nf*16+s)*784 + p] = sum_{c in split} l[n,c,f,p] * w[c]
__global__ __launch_bounds__(256) void k1_partial(
    const float* __restrict__ l, const float* __restrict__ w,
    float* __restrict__ part) {
  const int b = blockIdx.x;
  const int nf = b >> 4;
  const int s = b & 15;
  const int n = nf >> 4, f = nf & 15;
  const int t = threadIdx.x;
  if (t >= P4) return;  // 196 working threads; no syncthreads in this kernel

  const float* base = l + ((size_t)(n * C_ + s * CPS) * F_ + f) * WH_ + 4 * t;
  const float* wp = w + s * CPS;
  float4 acc = make_float4(0.f, 0.f, 0.f, 0.f);
#pragma unroll
  for (int j = 0; j < CPS; ++j) {
    const float wj = wp[j];  // wave-uniform -> scalar load
    const float4 v = *reinterpret_cast<const float4*>(base + (size_t)j * CH_STRIDE);
    acc.x = fmaf(v.x, wj, acc.x);
    acc.y = fmaf(v.y, wj, acc.y);
    acc.z = fmaf(v.z, wj, acc.z);
    acc.w = fmaf(v.w, wj, acc.w);
  }
  *reinterpret_cast<float4*>(part + (size_t)b * WH_ + 4 * t) = acc;
}

// ---- K2: reduce partials + gb -> c (d_out), softmax -> normalized a (ws)
__global__ __launch_bounds__(256) void k2_softmax(
    const float* __restrict__ part, const float* __restrict__ g,
    const float* __restrict__ w, float* __restrict__ out,
    float* __restrict__ a) {
  __shared__ float red[4];
  __shared__ float bc;
  const int nf = blockIdx.x;
  const int n = nf >> 4;
  const int t = threadIdx.x;
  const int lane = t & 63, wv = t >> 6;

  // gb = sum_c g[n,c]*w[c]  (256 threads, one c each)
  float gv = g[n * C_ + t] * w[t];
  gv = wave_reduce_sum(gv);
  if (lane == 0) red[wv] = gv;
  __syncthreads();
  if (t == 0) bc = red[0] + red[1] + red[2] + red[3];
  __syncthreads();
  const float gb = bc;

  float4 cv = make_float4(-3.4e38f, -3.4e38f, -3.4e38f, -3.4e38f);
  if (t < P4) {
    const float* pp = part + (size_t)nf * SPLITS * WH_ + 4 * t;
    float4 s0 = make_float4(0.f, 0.f, 0.f, 0.f);
#pragma unroll
    for (int s = 0; s < SPLITS; ++s) {
      const float4 v = *reinterpret_cast<const float4*>(pp + (size_t)s * WH_);
      s0.x += v.x; s0.y += v.y; s0.z += v.z; s0.w += v.w;
    }
    cv = make_float4(s0.x + gb, s0.y + gb, s0.z + gb, s0.w + gb);
    *reinterpret_cast<float4*>(out + (size_t)nf * WH_ + 4 * t) = cv;
  }

  // block max
  float m = fmaxf(fmaxf(cv.x, cv.y), fmaxf(cv.z, cv.w));
  m = wave_reduce_max(m);
  __syncthreads();
  if (lane == 0) red[wv] = m;
  __syncthreads();
  if (t == 0) bc = fmaxf(fmaxf(red[0], red[1]), fmaxf(red[2], red[3]));
  __syncthreads();
  const float cmax = bc;

  float4 e = make_float4(0.f, 0.f, 0.f, 0.f);
  if (t < P4) {
    e.x = expf(cv.x - cmax);
    e.y = expf(cv.y - cmax);
    e.z = expf(cv.z - cmax);
    e.w = expf(cv.w - cmax);
  }
  float ssum = (e.x + e.y) + (e.z + e.w);
  ssum = wave_reduce_sum(ssum);
  __syncthreads();
  if (lane == 0) red[wv] = ssum;
  __syncthreads();
  if (t == 0) bc = 1.f / (red[0] + red[1] + red[2] + red[3]);
  __syncthreads();
  const float inv = bc;

  if (t < P4) {
    e.x *= inv; e.y *= inv; e.z *= inv; e.w *= inv;
    *reinterpret_cast<float4*>(a + (size_t)nf * WH_ + 4 * t) = e;
  }
}

// ---- K3: pooling. One block per (n,c): g_out[n,c,f] = sum_p a[n,f,p]*l[n,c,f,p]
__global__ __launch_bounds__(256) void k3_pool(
    const float* __restrict__ l, const float* __restrict__ a,
    float* __restrict__ out) {
  const int b = blockIdx.x;  // n*C_ + c
  const int n = b >> 8;
  const int t = threadIdx.x, lane = t & 63, wv = t >> 6;
  const float* lb = l + (size_t)b * CH_STRIDE;    // l[n,c,0,0]
  const float* ab = a + (size_t)n * F_ * WH_;     // a[n,0,0]

#pragma unroll
  for (int i = 0; i < 4; ++i) {
    const int f = wv * 4 + i;
    const float4* lf = reinterpret_cast<const float4*>(lb + f * WH_);
    const float4* af = reinterpret_cast<const float4*>(ab + f * WH_);
    const float4 x0 = lf[lane],       y0 = af[lane];
    const float4 x1 = lf[lane + 64],  y1 = af[lane + 64];
    const float4 x2 = lf[lane + 128], y2 = af[lane + 128];
    float acc = 0.f;
    acc = fmaf(x0.x, y0.x, acc); acc = fmaf(x0.y, y0.y, acc);
    acc = fmaf(x0.z, y0.z, acc); acc = fmaf(x0.w, y0.w, acc);
    acc = fmaf(x1.x, y1.x, acc); acc = fmaf(x1.y, y1.y, acc);
    acc = fmaf(x1.z, y1.z, acc); acc = fmaf(x1.w, y1.w, acc);
    acc = fmaf(x2.x, y2.x, acc); acc = fmaf(x2.y, y2.y, acc);
    acc = fmaf(x2.z, y2.z, acc); acc = fmaf(x2.w, y2.w, acc);
    if (lane < 4) {
      const float4 x3 = lf[lane + 192], y3 = af[lane + 192];
      acc = fmaf(x3.x, y3.x, acc); acc = fmaf(x3.y, y3.y, acc);
      acc = fmaf(x3.z, y3.z, acc); acc = fmaf(x3.w, y3.w, acc);
    }
    acc = wave_reduce_sum(acc);
    if (lane == 0) out[COUT_SZ + (size_t)b * F_ + f] = acc;
  }
}

extern "C" void kernel_launch(void* const* d_in, const int* in_sizes, int n_in,
                              void* d_out, int out_size, void* d_ws, size_t ws_size,
                              hipStream_t stream) {
  const float* l = (const float*)d_in[0];
  const float* g = (const float*)d_in[1];
  const float* w = (const float*)d_in[2];
  float* out = (float*)d_out;
  float* part = (float*)d_ws;                        // 16*128*784 floats = 6.4 MB
  float* a = part + (size_t)SPLITS * NF * WH_;       // 128*784 floats = 0.4 MB

  k1_partial<<<dim3(NF * SPLITS), dim3(256), 0, stream>>>(l, w, part);
  k2_softmax<<<dim3(NF), dim3(256), 0, stream>>>(part, g, w, out, a);
  k3_pool<<<dim3(N_ * C_), dim3(256), 0, stream>>>(l, a, out);
}

// Round 4
// 168.260 us; speedup vs baseline: 1.0128x; 1.0128x over previous
//
#include <hip/hip_runtime.h>
#include <math.h>

// Problem constants (fixed by setup_inputs)
constexpr int N_ = 8, C_ = 256, F_ = 16, WH_ = 784;
constexpr int NF = N_ * F_;          // 128
constexpr int CH_STRIDE = F_ * WH_;  // 12544 floats between channels
constexpr int SPLITS = 16;           // channel splits in K1
constexpr int CPS = C_ / SPLITS;     // 16 channels per split
constexpr int COUT_SZ = NF * WH_;    // 100352 floats (c output)
constexpr int P4 = WH_ / 4;          // 196 float4 per spatial row

__device__ inline float wave_reduce_sum(float v) {
#pragma unroll
  for (int o = 32; o > 0; o >>= 1) v += __shfl_down(v, o, 64);
  return v;
}
__device__ inline float wave_reduce_max(float v) {
#pragma unroll
  for (int o = 32; o > 0; o >>= 1) v = fmaxf(v, __shfl_down(v, o, 64));
  return v;
}

// ---- K1: partial channel-dot. Block b: nf = b>>4, split s = b&15.
// part[(nf*16+s)*784 + p] = sum_{c in split} l[n,c,f,p] * w[c]
__global__ __launch_bounds__(256) void k1_partial(
    const float* __restrict__ l, const float* __restrict__ w,
    float* __restrict__ part) {
  const int b = blockIdx.x;
  const int nf = b >> 4;
  const int s = b & 15;
  const int n = nf >> 4, f = nf & 15;
  const int t = threadIdx.x;
  if (t >= P4) return;  // 196 working threads; no syncthreads in this kernel

  const float* base = l + ((size_t)(n * C_ + s * CPS) * F_ + f) * WH_ + 4 * t;
  const float* wp = w + s * CPS;
  float4 acc = make_float4(0.f, 0.f, 0.f, 0.f);
#pragma unroll
  for (int j = 0; j < CPS; ++j) {
    const float wj = wp[j];  // wave-uniform -> scalar load
    const float4 v = *reinterpret_cast<const float4*>(base + (size_t)j * CH_STRIDE);
    acc.x = fmaf(v.x, wj, acc.x);
    acc.y = fmaf(v.y, wj, acc.y);
    acc.z = fmaf(v.z, wj, acc.z);
    acc.w = fmaf(v.w, wj, acc.w);
  }
  *reinterpret_cast<float4*>(part + (size_t)b * WH_ + 4 * t) = acc;
}

// ---- K2: reduce partials + gb -> c (d_out), softmax -> normalized a (ws)
__global__ __launch_bounds__(256) void k2_softmax(
    const float* __restrict__ part, const float* __restrict__ g,
    const float* __restrict__ w, float* __restrict__ out,
    float* __restrict__ a) {
  __shared__ float red[4];
  __shared__ float bc;
  const int nf = blockIdx.x;
  const int n = nf >> 4;
  const int t = threadIdx.x;
  const int lane = t & 63, wv = t >> 6;

  // gb = sum_c g[n,c]*w[c]  (256 threads, one c each)
  float gv = g[n * C_ + t] * w[t];
  gv = wave_reduce_sum(gv);
  if (lane == 0) red[wv] = gv;
  __syncthreads();
  if (t == 0) bc = red[0] + red[1] + red[2] + red[3];
  __syncthreads();
  const float gb = bc;

  float4 cv = make_float4(-3.4e38f, -3.4e38f, -3.4e38f, -3.4e38f);
  if (t < P4) {
    const float* pp = part + (size_t)nf * SPLITS * WH_ + 4 * t;
    float4 s0 = make_float4(0.f, 0.f, 0.f, 0.f);
#pragma unroll
    for (int s = 0; s < SPLITS; ++s) {
      const float4 v = *reinterpret_cast<const float4*>(pp + (size_t)s * WH_);
      s0.x += v.x; s0.y += v.y; s0.z += v.z; s0.w += v.w;
    }
    cv = make_float4(s0.x + gb, s0.y + gb, s0.z + gb, s0.w + gb);
    *reinterpret_cast<float4*>(out + (size_t)nf * WH_ + 4 * t) = cv;
  }

  // block max
  float m = fmaxf(fmaxf(cv.x, cv.y), fmaxf(cv.z, cv.w));
  m = wave_reduce_max(m);
  __syncthreads();
  if (lane == 0) red[wv] = m;
  __syncthreads();
  if (t == 0) bc = fmaxf(fmaxf(red[0], red[1]), fmaxf(red[2], red[3]));
  __syncthreads();
  const float cmax = bc;

  float4 e = make_float4(0.f, 0.f, 0.f, 0.f);
  if (t < P4) {
    e.x = expf(cv.x - cmax);
    e.y = expf(cv.y - cmax);
    e.z = expf(cv.z - cmax);
    e.w = expf(cv.w - cmax);
  }
  float ssum = (e.x + e.y) + (e.z + e.w);
  ssum = wave_reduce_sum(ssum);
  __syncthreads();
  if (lane == 0) red[wv] = ssum;
  __syncthreads();
  if (t == 0) bc = 1.f / (red[0] + red[1] + red[2] + red[3]);
  __syncthreads();
  const float inv = bc;

  if (t < P4) {
    e.x *= inv; e.y *= inv; e.z *= inv; e.w *= inv;
    *reinterpret_cast<float4*>(a + (size_t)nf * WH_ + 4 * t) = e;
  }
}

// ---- K3: pooling. Block b = (n, f, cg): 16 channels per block, 4 per wave.
// Wave register-caches its slice of a[n,f,:] ONCE, reuses across 4 channels.
__global__ __launch_bounds__(256) void k3_pool(
    const float* __restrict__ l, const float* __restrict__ a,
    float* __restrict__ out) {
  const int b = blockIdx.x;        // [0, 2048): n*256 + f*16 + cg
  const int n = b >> 8;
  const int f = (b >> 4) & 15;
  const int cg = b & 15;
  const int t = threadIdx.x, lane = t & 63, wv = t >> 6;
  const int p0 = lane << 2;

  const float* ar = a + ((size_t)n * F_ + f) * WH_;
  const float4 a0 = *reinterpret_cast<const float4*>(ar + p0);
  const float4 a1 = *reinterpret_cast<const float4*>(ar + p0 + 256);
  const float4 a2 = *reinterpret_cast<const float4*>(ar + p0 + 512);
  float4 a3 = make_float4(0.f, 0.f, 0.f, 0.f);
  if (lane < 4) a3 = *reinterpret_cast<const float4*>(ar + 768 + p0);

  const int c0 = cg * 16 + wv * 4;  // this wave's first channel
#pragma unroll
  for (int k = 0; k < 4; ++k) {
    const int c = c0 + k;
    const float* lr = l + ((size_t)(n * C_ + c) * F_ + f) * WH_;
    const float4 x0 = *reinterpret_cast<const float4*>(lr + p0);
    const float4 x1 = *reinterpret_cast<const float4*>(lr + p0 + 256);
    const float4 x2 = *reinterpret_cast<const float4*>(lr + p0 + 512);
    float acc = 0.f;
    acc = fmaf(x0.x, a0.x, acc); acc = fmaf(x0.y, a0.y, acc);
    acc = fmaf(x0.z, a0.z, acc); acc = fmaf(x0.w, a0.w, acc);
    acc = fmaf(x1.x, a1.x, acc); acc = fmaf(x1.y, a1.y, acc);
    acc = fmaf(x1.z, a1.z, acc); acc = fmaf(x1.w, a1.w, acc);
    acc = fmaf(x2.x, a2.x, acc); acc = fmaf(x2.y, a2.y, acc);
    acc = fmaf(x2.z, a2.z, acc); acc = fmaf(x2.w, a2.w, acc);
    if (lane < 4) {
      const float4 x3 = *reinterpret_cast<const float4*>(lr + 768 + p0);
      acc = fmaf(x3.x, a3.x, acc); acc = fmaf(x3.y, a3.y, acc);
      acc = fmaf(x3.z, a3.z, acc); acc = fmaf(x3.w, a3.w, acc);
    }
    acc = wave_reduce_sum(acc);
    if (lane == 0) out[COUT_SZ + (size_t)(n * C_ + c) * F_ + f] = acc;
  }
}

extern "C" void kernel_launch(void* const* d_in, const int* in_sizes, int n_in,
                              void* d_out, int out_size, void* d_ws, size_t ws_size,
                              hipStream_t stream) {
  const float* l = (const float*)d_in[0];
  const float* g = (const float*)d_in[1];
  const float* w = (const float*)d_in[2];
  float* out = (float*)d_out;
  float* part = (float*)d_ws;                        // 16*128*784 floats = 6.4 MB
  float* a = part + (size_t)SPLITS * NF * WH_;       // 128*784 floats = 0.4 MB

  k1_partial<<<dim3(NF * SPLITS), dim3(256), 0, stream>>>(l, w, part);
  k2_softmax<<<dim3(NF), dim3(256), 0, stream>>>(part, g, w, out, a);
  k3_pool<<<dim3(N_ * C_ * F_ / 16), dim3(256), 0, stream>>>(l, a, out);
}